// Round 1
// baseline (292.325 us; speedup 1.0000x reference)
//
#include <hip/hip_runtime.h>
#include <hip/hip_bf16.h>

// SelfAttention: x(2,2048,1024) fp32; Wq/Wk/Wv/Wu (1024,1024); bu(1024)
// y = softmax((xWq^T)(xWk^T)^T / 32) (xWv^T) @ Wu^T + bu   (per 16 heads of 64)
// Strategy: bf16 MFMA (16x16x32) everywhere, fp32 accum.

typedef __bf16 bf16x8 __attribute__((ext_vector_type(8)));
typedef float f32x4 __attribute__((ext_vector_type(4)));

static __device__ __forceinline__ unsigned short f2bf(float f) {
  union { float f; unsigned u; } a; a.f = f;
  unsigned r = a.u + 0x7fff + ((a.u >> 16) & 1);   // RNE
  return (unsigned short)(r >> 16);
}

__global__ __launch_bounds__(256)
void cast_kernel(const float* __restrict__ in, unsigned short* __restrict__ out, int n) {
  int idx = (blockIdx.x * 256 + threadIdx.x) * 4;
  if (idx < n) {
    float4 v = *(const float4*)&in[idx];
    ushort4 o;
    o.x = f2bf(v.x); o.y = f2bf(v.y); o.z = f2bf(v.z); o.w = f2bf(v.w);
    *(ushort4*)&out[idx] = o;
  }
}

// C[M][N] = A[M][K] * B[N][K]^T  (both K-contiguous, bf16, fp32 accum)
// EPI=0: scatter bf16 to dst[((b*16+h)*2048+t)*64+s]  (m=(b,t), n=(h,s))
// EPI=1: fp32 out[m*N+n] = acc + bias[n]
template<int EPI>
__global__ __launch_bounds__(256)
void gemm_bt(const unsigned short* __restrict__ A,
             const unsigned short* __restrict__ B,
             unsigned short* __restrict__ Cb,
             float* __restrict__ Cf,
             const float* __restrict__ bias,
             int M, int N, int Ksz)
{
  __shared__ unsigned short As[128][40];   // pad 32->40: 2-way conflicts only
  __shared__ unsigned short Bs[128][40];
  const int tid  = threadIdx.x;
  const int lane = tid & 63;
  const int wid  = tid >> 6;
  const int wr   = wid >> 1, wc = wid & 1;          // 2x2 wave grid, 64x64/wave
  const int g    = lane >> 4, r = lane & 15;
  const int bm   = blockIdx.x * 128, bn = blockIdx.y * 128;

  f32x4 acc[4][4] = {};

  const int srow = tid >> 2;         // 0..63
  const int scol = (tid & 3) * 8;    // 0,8,16,24

  for (int k0 = 0; k0 < Ksz; k0 += 32) {
    __syncthreads();
    *(bf16x8*)&As[srow     ][scol] = *(const bf16x8*)&A[(size_t)(bm + srow     ) * Ksz + k0 + scol];
    *(bf16x8*)&As[srow + 64][scol] = *(const bf16x8*)&A[(size_t)(bm + srow + 64) * Ksz + k0 + scol];
    *(bf16x8*)&Bs[srow     ][scol] = *(const bf16x8*)&B[(size_t)(bn + srow     ) * Ksz + k0 + scol];
    *(bf16x8*)&Bs[srow + 64][scol] = *(const bf16x8*)&B[(size_t)(bn + srow + 64) * Ksz + k0 + scol];
    __syncthreads();
    bf16x8 af[4], bfr[4];
#pragma unroll
    for (int mi = 0; mi < 4; ++mi) af[mi]  = *(const bf16x8*)&As[wr*64 + mi*16 + r][g*8];
#pragma unroll
    for (int ni = 0; ni < 4; ++ni) bfr[ni] = *(const bf16x8*)&Bs[wc*64 + ni*16 + r][g*8];
#pragma unroll
    for (int mi = 0; mi < 4; ++mi)
#pragma unroll
      for (int ni = 0; ni < 4; ++ni)
        acc[mi][ni] = __builtin_amdgcn_mfma_f32_16x16x32_bf16(af[mi], bfr[ni], acc[mi][ni], 0, 0, 0);
  }

#pragma unroll
  for (int mi = 0; mi < 4; ++mi)
#pragma unroll
    for (int ni = 0; ni < 4; ++ni)
#pragma unroll
      for (int q = 0; q < 4; ++q) {
        int m = bm + wr*64 + mi*16 + g*4 + q;      // C/D layout: row=(l>>4)*4+reg
        int n = bn + wc*64 + ni*16 + r;            //             col=l&15
        float v = acc[mi][ni][q];
        if (EPI == 0) {
          int b = m >> 11, t = m & 2047;
          int h = n >> 6,  s = n & 63;
          Cb[((size_t)((b*16 + h)*2048 + t))*64 + s] = f2bf(v);
        } else {
          Cf[(size_t)m * N + n] = v + bias[n];
        }
      }
}

// Flash attention: grid (T/64, B*H). 4 waves x 16 q-rows. KVBLK=128.
__global__ __launch_bounds__(256)
void attn_kernel(const unsigned short* __restrict__ Qg,
                 const unsigned short* __restrict__ Kg,
                 const unsigned short* __restrict__ Vg,
                 unsigned short* __restrict__ Og)
{
  const int T = 2048;
  __shared__ unsigned short Ks[128][72];       // [kv][s], pad 64->72
  __shared__ unsigned short Vt[64][136];       // [s][kv], pad 128->136
  __shared__ unsigned short Pl[4][16][136];    // per-wave P tile [q][kv]

  const int tid = threadIdx.x, lane = tid & 63, wid = tid >> 6;
  const int g = lane >> 4, r = lane & 15;
  const int bh = blockIdx.y;
  const int qbase = blockIdx.x * 64;
  const size_t base = (size_t)bh * T * 64;
  const unsigned short* Qh = Qg + base;
  const unsigned short* Kh = Kg + base;
  const unsigned short* Vh = Vg + base;

  // Q fragments in registers (A operand: row = l&15, k = g*8.. contiguous)
  bf16x8 qa[2];
  {
    const int qrow = qbase + wid*16 + r;
#pragma unroll
    for (int ks = 0; ks < 2; ++ks)
      qa[ks] = *(const bf16x8*)&Qh[(size_t)qrow*64 + ks*32 + g*8];
  }

  f32x4 acc_o[4] = {};
  float mrun[4], lrun[4];
#pragma unroll
  for (int q = 0; q < 4; ++q) { mrun[q] = -1e30f; lrun[q] = 0.f; }

  const int srowS = tid >> 3;        // 0..31
  const int scol8 = (tid & 7) * 8;   // 0..56

  for (int kv0 = 0; kv0 < T; kv0 += 128) {
    __syncthreads();
#pragma unroll
    for (int it = 0; it < 4; ++it) {
      int row = srowS + it*32;
      bf16x8 kvv = *(const bf16x8*)&Kh[(size_t)(kv0+row)*64 + scol8];
      *(bf16x8*)&Ks[row][scol8] = kvv;
      bf16x8 vv = *(const bf16x8*)&Vh[(size_t)(kv0+row)*64 + scol8];
#pragma unroll
      for (int j = 0; j < 8; ++j)
        Vt[scol8 + j][row] = ((unsigned short*)&vv)[j];   // transpose write
    }
    __syncthreads();

    // S = Q K^T * (1/32)
    f32x4 accs[8];
#pragma unroll
    for (int nt = 0; nt < 8; ++nt) {
      f32x4 a = {};
#pragma unroll
      for (int ks = 0; ks < 2; ++ks) {
        bf16x8 kb = *(const bf16x8*)&Ks[nt*16 + r][ks*32 + g*8];
        a = __builtin_amdgcn_mfma_f32_16x16x32_bf16(qa[ks], kb, a, 0, 0, 0);
      }
      accs[nt] = a;
    }

    // online softmax (rows live at (l>>4)*4+q across 16-lane groups)
    float tmax[4];
#pragma unroll
    for (int q = 0; q < 4; ++q) tmax[q] = -1e30f;
#pragma unroll
    for (int nt = 0; nt < 8; ++nt)
#pragma unroll
      for (int q = 0; q < 4; ++q) {
        float s = accs[nt][q] * 0.03125f;
        accs[nt][q] = s;
        tmax[q] = fmaxf(tmax[q], s);
      }
#pragma unroll
    for (int q = 0; q < 4; ++q)
#pragma unroll
      for (int msk = 1; msk < 16; msk <<= 1)
        tmax[q] = fmaxf(tmax[q], __shfl_xor(tmax[q], msk, 64));

    float fq[4], rs[4];
#pragma unroll
    for (int q = 0; q < 4; ++q) {
      float mnew = fmaxf(mrun[q], tmax[q]);
      fq[q] = __expf(mrun[q] - mnew);
      mrun[q] = mnew;
      rs[q] = 0.f;
    }
#pragma unroll
    for (int nt = 0; nt < 8; ++nt)
#pragma unroll
      for (int q = 0; q < 4; ++q) {
        float p = __expf(accs[nt][q] - mrun[q]);
        rs[q] += p;
        Pl[wid][g*4 + q][nt*16 + r] = f2bf(p);
      }
#pragma unroll
    for (int q = 0; q < 4; ++q) {
#pragma unroll
      for (int msk = 1; msk < 16; msk <<= 1)
        rs[q] += __shfl_xor(rs[q], msk, 64);
      lrun[q] = lrun[q]*fq[q] + rs[q];
    }
#pragma unroll
    for (int st = 0; st < 4; ++st)
#pragma unroll
      for (int q = 0; q < 4; ++q)
        acc_o[st][q] *= fq[q];

    __syncthreads();   // P visible (conservative; also fences Ks/Vt reads)

    // O += P V
    bf16x8 pa[4];
#pragma unroll
    for (int ks = 0; ks < 4; ++ks)
      pa[ks] = *(const bf16x8*)&Pl[wid][r][ks*32 + g*8];
#pragma unroll
    for (int st = 0; st < 4; ++st)
#pragma unroll
      for (int ks = 0; ks < 4; ++ks) {
        bf16x8 vb = *(const bf16x8*)&Vt[st*16 + r][ks*32 + g*8];
        acc_o[st] = __builtin_amdgcn_mfma_f32_16x16x32_bf16(pa[ks], vb, acc_o[st], 0, 0, 0);
      }
  }

  // epilogue: O/l -> Og[b][t][h*64+s] (bf16, A-layout for final GEMM)
  const int h = bh & 15, b = bh >> 4;
#pragma unroll
  for (int st = 0; st < 4; ++st)
#pragma unroll
    for (int q = 0; q < 4; ++q) {
      int trow = qbase + wid*16 + g*4 + q;
      int col  = h*64 + st*16 + r;
      float v = acc_o[st][q] / lrun[q];
      Og[((size_t)(b*2048 + trow))*1024 + col] = f2bf(v);
    }
}

extern "C" void kernel_launch(void* const* d_in, const int* in_sizes, int n_in,
                              void* d_out, int out_size, void* d_ws, size_t ws_size,
                              hipStream_t stream) {
  const float* x  = (const float*)d_in[0];
  const float* Wq = (const float*)d_in[1];
  const float* Wk = (const float*)d_in[2];
  const float* Wv = (const float*)d_in[3];
  const float* Wu = (const float*)d_in[4];
  const float* bu = (const float*)d_in[5];
  float* out = (float*)d_out;

  char* ws = (char*)d_ws;
  unsigned short* xb  = (unsigned short*)(ws);                 // 8 MB  (also reused as attn out)
  unsigned short* Wqb = (unsigned short*)(ws + (size_t)( 8<<20));
  unsigned short* Wkb = (unsigned short*)(ws + (size_t)(10<<20));
  unsigned short* Wvb = (unsigned short*)(ws + (size_t)(12<<20));
  unsigned short* Wub = (unsigned short*)(ws + (size_t)(14<<20));
  unsigned short* Qg  = (unsigned short*)(ws + (size_t)(16<<20));
  unsigned short* Kg  = (unsigned short*)(ws + (size_t)(24<<20));
  unsigned short* Vg  = (unsigned short*)(ws + (size_t)(32<<20));
  unsigned short* Ab  = xb;  // attn output overlays xb (xb dead after QKV GEMMs)

  cast_kernel<<<dim3(4096*1024/4/256), 256, 0, stream>>>(x,  xb,  4096*1024);
  cast_kernel<<<dim3(1024*1024/4/256), 256, 0, stream>>>(Wq, Wqb, 1024*1024);
  cast_kernel<<<dim3(1024*1024/4/256), 256, 0, stream>>>(Wk, Wkb, 1024*1024);
  cast_kernel<<<dim3(1024*1024/4/256), 256, 0, stream>>>(Wv, Wvb, 1024*1024);
  cast_kernel<<<dim3(1024*1024/4/256), 256, 0, stream>>>(Wu, Wub, 1024*1024);

  dim3 gg(4096/128, 1024/128);
  gemm_bt<0><<<gg, 256, 0, stream>>>(xb, Wqb, Qg, nullptr, nullptr, 4096, 1024, 1024);
  gemm_bt<0><<<gg, 256, 0, stream>>>(xb, Wkb, Kg, nullptr, nullptr, 4096, 1024, 1024);
  gemm_bt<0><<<gg, 256, 0, stream>>>(xb, Wvb, Vg, nullptr, nullptr, 4096, 1024, 1024);

  attn_kernel<<<dim3(2048/64, 32), 256, 0, stream>>>(Qg, Kg, Vg, Ab);

  gemm_bt<1><<<gg, 256, 0, stream>>>(Ab, Wub, nullptr, out, bu, 4096, 1024, 1024);
}

// Round 2
// 261.212 us; speedup vs baseline: 1.1191x; 1.1191x over previous
//
#include <hip/hip_runtime.h>
#include <hip/hip_bf16.h>

// SelfAttention: x(2,2048,1024) fp32; Wq/Wk/Wv/Wu (1024,1024); bu(1024)
// y = softmax((xWq^T)(xWk^T)^T / 32) (xWv^T) @ Wu^T + bu   (16 heads of 64)
// bf16 MFMA 16x16x32, fp32 accum. V stored transposed in global so attention
// needs NO K/V LDS staging (L2-served fragment loads) and NO barriers.

typedef __bf16 bf16x8 __attribute__((ext_vector_type(8)));
typedef float f32x4 __attribute__((ext_vector_type(4)));

static __device__ __forceinline__ unsigned short f2bf(float f) {
  union { float f; unsigned u; } a; a.f = f;
  unsigned r = a.u + 0x7fff + ((a.u >> 16) & 1);   // RNE
  return (unsigned short)(r >> 16);
}

static __device__ __forceinline__ void gload_lds16(const unsigned short* g, unsigned short* l) {
  __builtin_amdgcn_global_load_lds((const __attribute__((address_space(1))) void*)g,
                                   (__attribute__((address_space(3))) void*)l, 16, 0, 0);
}

// Fused bf16 casts: x (4M elems) + 4 weights (1M each). 1024 elems/block.
__global__ __launch_bounds__(256)
void cast_all(const float* __restrict__ x, const float* __restrict__ wq,
              const float* __restrict__ wk, const float* __restrict__ wv,
              const float* __restrict__ wu,
              unsigned short* __restrict__ xb, unsigned short* __restrict__ wqb,
              unsigned short* __restrict__ wkb, unsigned short* __restrict__ wvb,
              unsigned short* __restrict__ wub)
{
  int bid = blockIdx.x;
  const float* src; unsigned short* dst; int blk;
  if (bid < 4096)      { src = x;  dst = xb;  blk = bid; }
  else if (bid < 5120) { src = wq; dst = wqb; blk = bid - 4096; }
  else if (bid < 6144) { src = wk; dst = wkb; blk = bid - 5120; }
  else if (bid < 7168) { src = wv; dst = wvb; blk = bid - 6144; }
  else                 { src = wu; dst = wub; blk = bid - 7168; }
  int idx = blk * 1024 + threadIdx.x * 4;
  float4 v = *(const float4*)&src[idx];
  ushort4 o;
  o.x = f2bf(v.x); o.y = f2bf(v.y); o.z = f2bf(v.z); o.w = f2bf(v.w);
  *(ushort4*)&dst[idx] = o;
}

// C[M][N] = A[M][K] * B[N][K]^T (bf16, fp32 accum). 128x128 tile, 8 waves
// (2x4 of 64x32), BK=32, global_load_lds width-16 staging, linear LDS.
// EPI=0: scatter bf16 to Q/K layout [b,h][t][s]
// EPI=1: fp32 out[m*N+n] = acc + bias[n]
// EPI=2: scatter bf16 to V^T layout [b,h][s][t] (ushort4-packed over t)
template<int EPI>
__global__ __launch_bounds__(512, 2)
void gemm_bt(const unsigned short* __restrict__ A,
             const unsigned short* __restrict__ B,
             unsigned short* __restrict__ Cb,
             float* __restrict__ Cf,
             const float* __restrict__ bias,
             int M, int N, int Ksz)
{
  __shared__ __align__(16) unsigned short As[128 * 32];
  __shared__ __align__(16) unsigned short Bs[128 * 32];
  const int tid  = threadIdx.x;
  const int lane = tid & 63;
  const int wid  = tid >> 6;          // 0..7
  const int wr   = wid >> 2, wc = wid & 3;   // 2x4 wave grid, 64x32 per wave
  const int g    = lane >> 4, r = lane & 15;
  const int bm   = blockIdx.x * 128, bn = blockIdx.y * 128;

  f32x4 acc[4][2] = {};

  // staging: chunk wid covers rows wid*16..wid*16+15 (1 KB per chunk)
  const int grow = lane >> 2;          // 0..15
  const int gcol = (lane & 3) * 8;     // 0,8,16,24
  const unsigned short* Ag = &A[(size_t)(bm + wid*16 + grow) * Ksz + gcol];
  const unsigned short* Bg = &B[(size_t)(bn + wid*16 + grow) * Ksz + gcol];
  unsigned short* AsW = &As[wid * 512];   // wave-uniform LDS base
  unsigned short* BsW = &Bs[wid * 512];

  for (int k0 = 0; k0 < Ksz; k0 += 32) {
    __syncthreads();
    gload_lds16(Ag + k0, AsW);
    gload_lds16(Bg + k0, BsW);
    __syncthreads();   // compiler drains vmcnt(0) before barrier
    bf16x8 af[4], bfr[2];
#pragma unroll
    for (int mi = 0; mi < 4; ++mi)
      af[mi] = *(const bf16x8*)&As[(wr*64 + mi*16 + r) * 32 + g*8];
#pragma unroll
    for (int ni = 0; ni < 2; ++ni)
      bfr[ni] = *(const bf16x8*)&Bs[(wc*32 + ni*16 + r) * 32 + g*8];
#pragma unroll
    for (int mi = 0; mi < 4; ++mi)
#pragma unroll
      for (int ni = 0; ni < 2; ++ni)
        acc[mi][ni] = __builtin_amdgcn_mfma_f32_16x16x32_bf16(af[mi], bfr[ni], acc[mi][ni], 0, 0, 0);
  }

#pragma unroll
  for (int mi = 0; mi < 4; ++mi)
#pragma unroll
    for (int ni = 0; ni < 2; ++ni) {
      if (EPI == 2) {
        int m0 = bm + wr*64 + mi*16 + g*4;
        int n  = bn + wc*32 + ni*16 + r;
        int b = m0 >> 11, t0 = m0 & 2047;
        int h = n >> 6,  s = n & 63;
        ushort4 o;
        o.x = f2bf(acc[mi][ni][0]); o.y = f2bf(acc[mi][ni][1]);
        o.z = f2bf(acc[mi][ni][2]); o.w = f2bf(acc[mi][ni][3]);
        *(ushort4*)&Cb[((size_t)((b*16 + h)*64 + s)) * 2048 + t0] = o;
      } else {
#pragma unroll
        for (int q = 0; q < 4; ++q) {
          int m = bm + wr*64 + mi*16 + g*4 + q;   // C/D: row=(l>>4)*4+reg
          int n = bn + wc*32 + ni*16 + r;         //      col=l&15
          float v = acc[mi][ni][q];
          if (EPI == 0) {
            int b = m >> 11, t = m & 2047;
            int h = n >> 6,  s = n & 63;
            Cb[((size_t)((b*16 + h)*2048 + t)) * 64 + s] = f2bf(v);
          } else {
            Cf[(size_t)m * N + n] = v + bias[n];
          }
        }
      }
    }
}

// Flash attention, barrier-free. grid (T/128, B*H), 4 waves x 32 q-rows.
// K [bh][t][s] and V^T [bh][s][t] fragments loaded directly from global (L2).
// Only LDS use: per-wave P transpose buffer.
__global__ __launch_bounds__(256, 2)
void attn_kernel(const unsigned short* __restrict__ Qg,
                 const unsigned short* __restrict__ Kg,
                 const unsigned short* __restrict__ Vtg,
                 unsigned short* __restrict__ Og)
{
  const int T = 2048;
  __shared__ __align__(16) unsigned short Pl[4][32][136];  // 272B rows: 16B-aligned

  const int tid = threadIdx.x, lane = tid & 63, wid = tid >> 6;
  const int g = lane >> 4, r = lane & 15;
  const int bh = blockIdx.y;
  const int qbase = blockIdx.x * 128 + wid * 32;
  const size_t base = (size_t)bh * T * 64;
  const unsigned short* Qh = Qg + base;
  const unsigned short* Kh = Kg + base;
  const unsigned short* Vh = Vtg + base;    // [s][t], s-stride 2048

  // Q fragments (A operand: row=l&15, k contiguous), 2 m-tiles of 16 rows
  bf16x8 qa[2][2];
#pragma unroll
  for (int m = 0; m < 2; ++m)
#pragma unroll
    for (int ks = 0; ks < 2; ++ks)
      qa[m][ks] = *(const bf16x8*)&Qh[(size_t)(qbase + m*16 + r)*64 + ks*32 + g*8];

  f32x4 acc_o[2][4] = {};
  float mrun[2][4], lrun[2][4];
#pragma unroll
  for (int m = 0; m < 2; ++m)
#pragma unroll
    for (int q = 0; q < 4; ++q) { mrun[m][q] = -1e30f; lrun[m][q] = 0.f; }

  for (int kv0 = 0; kv0 < T; kv0 += 128) {
    // S = Q K^T : K fragments straight from global, reused for both m-tiles
    f32x4 accs[2][8];
#pragma unroll
    for (int nt = 0; nt < 8; ++nt) {
      const unsigned short* kp = &Kh[(size_t)(kv0 + nt*16 + r)*64 + g*8];
      bf16x8 kb0 = *(const bf16x8*)kp;
      bf16x8 kb1 = *(const bf16x8*)(kp + 32);
      f32x4 a0 = {}, a1 = {};
      a0 = __builtin_amdgcn_mfma_f32_16x16x32_bf16(qa[0][0], kb0, a0, 0, 0, 0);
      a0 = __builtin_amdgcn_mfma_f32_16x16x32_bf16(qa[0][1], kb1, a0, 0, 0, 0);
      a1 = __builtin_amdgcn_mfma_f32_16x16x32_bf16(qa[1][0], kb0, a1, 0, 0, 0);
      a1 = __builtin_amdgcn_mfma_f32_16x16x32_bf16(qa[1][1], kb1, a1, 0, 0, 0);
      accs[0][nt] = a0; accs[1][nt] = a1;
    }

    // online softmax per m-tile (row = g*4+q within tile, cols across r)
#pragma unroll
    for (int m = 0; m < 2; ++m) {
      float tmax[4];
#pragma unroll
      for (int q = 0; q < 4; ++q) tmax[q] = -1e30f;
#pragma unroll
      for (int nt = 0; nt < 8; ++nt)
#pragma unroll
        for (int q = 0; q < 4; ++q) {
          float s = accs[m][nt][q] * 0.03125f;
          accs[m][nt][q] = s;
          tmax[q] = fmaxf(tmax[q], s);
        }
#pragma unroll
      for (int q = 0; q < 4; ++q)
#pragma unroll
        for (int msk = 1; msk < 16; msk <<= 1)
          tmax[q] = fmaxf(tmax[q], __shfl_xor(tmax[q], msk, 64));

      float fq[4], rs[4];
#pragma unroll
      for (int q = 0; q < 4; ++q) {
        float mnew = fmaxf(mrun[m][q], tmax[q]);
        fq[q] = __expf(mrun[m][q] - mnew);
        mrun[m][q] = mnew;
        rs[q] = 0.f;
      }
#pragma unroll
      for (int nt = 0; nt < 8; ++nt)
#pragma unroll
        for (int q = 0; q < 4; ++q) {
          float p = __expf(accs[m][nt][q] - mrun[m][q]);
          rs[q] += p;
          Pl[wid][m*16 + g*4 + q][nt*16 + r] = f2bf(p);
        }
#pragma unroll
      for (int q = 0; q < 4; ++q) {
#pragma unroll
        for (int msk = 1; msk < 16; msk <<= 1)
          rs[q] += __shfl_xor(rs[q], msk, 64);
        lrun[m][q] = lrun[m][q] * fq[q] + rs[q];
      }
#pragma unroll
      for (int st = 0; st < 4; ++st)
#pragma unroll
        for (int q = 0; q < 4; ++q)
          acc_o[m][st][q] *= fq[q];
    }
    // Pl write->read is same-wave: DS ops are wave-ordered, no barrier needed

    // O += P V : V^T fragments from global, reused for both m-tiles
#pragma unroll
    for (int ks = 0; ks < 4; ++ks) {
      bf16x8 pa0 = *(const bf16x8*)&Pl[wid][r     ][ks*32 + g*8];
      bf16x8 pa1 = *(const bf16x8*)&Pl[wid][16 + r][ks*32 + g*8];
#pragma unroll
      for (int st = 0; st < 4; ++st) {
        bf16x8 vb = *(const bf16x8*)&Vh[(size_t)(st*16 + r)*T + kv0 + ks*32 + g*8];
        acc_o[0][st] = __builtin_amdgcn_mfma_f32_16x16x32_bf16(pa0, vb, acc_o[0][st], 0, 0, 0);
        acc_o[1][st] = __builtin_amdgcn_mfma_f32_16x16x32_bf16(pa1, vb, acc_o[1][st], 0, 0, 0);
      }
    }
  }

  // epilogue: O/l -> Og[b][t][h*64+s] (bf16, A-layout for final GEMM)
  const int h = bh & 15, b = bh >> 4;
#pragma unroll
  for (int m = 0; m < 2; ++m)
#pragma unroll
    for (int st = 0; st < 4; ++st)
#pragma unroll
      for (int q = 0; q < 4; ++q) {
        int trow = qbase + m*16 + g*4 + q;
        int col  = h*64 + st*16 + r;
        float v = acc_o[m][st][q] / lrun[m][q];
        Og[((size_t)(b*2048 + trow))*1024 + col] = f2bf(v);
      }
}

extern "C" void kernel_launch(void* const* d_in, const int* in_sizes, int n_in,
                              void* d_out, int out_size, void* d_ws, size_t ws_size,
                              hipStream_t stream) {
  const float* x  = (const float*)d_in[0];
  const float* Wq = (const float*)d_in[1];
  const float* Wk = (const float*)d_in[2];
  const float* Wv = (const float*)d_in[3];
  const float* Wu = (const float*)d_in[4];
  const float* bu = (const float*)d_in[5];
  float* out = (float*)d_out;

  char* ws = (char*)d_ws;
  unsigned short* xb  = (unsigned short*)(ws);                 // 8 MB (reused as attn out)
  unsigned short* Wqb = (unsigned short*)(ws + (size_t)( 8<<20));
  unsigned short* Wkb = (unsigned short*)(ws + (size_t)(10<<20));
  unsigned short* Wvb = (unsigned short*)(ws + (size_t)(12<<20));
  unsigned short* Wub = (unsigned short*)(ws + (size_t)(14<<20));
  unsigned short* Qg  = (unsigned short*)(ws + (size_t)(16<<20));
  unsigned short* Kg  = (unsigned short*)(ws + (size_t)(24<<20));
  unsigned short* Vtg = (unsigned short*)(ws + (size_t)(32<<20));
  unsigned short* Ab  = xb;  // attn output overlays xb (dead after QKV GEMMs)

  cast_all<<<dim3(8192), 256, 0, stream>>>(x, Wq, Wk, Wv, Wu, xb, Wqb, Wkb, Wvb, Wub);

  dim3 gg(4096/128, 1024/128);
  gemm_bt<0><<<gg, 512, 0, stream>>>(xb, Wqb, Qg,  nullptr, nullptr, 4096, 1024, 1024);
  gemm_bt<0><<<gg, 512, 0, stream>>>(xb, Wkb, Kg,  nullptr, nullptr, 4096, 1024, 1024);
  gemm_bt<2><<<gg, 512, 0, stream>>>(xb, Wvb, Vtg, nullptr, nullptr, 4096, 1024, 1024);

  attn_kernel<<<dim3(2048/128, 32), 256, 0, stream>>>(Qg, Kg, Vtg, Ab);

  gemm_bt<1><<<gg, 512, 0, stream>>>(Ab, Wub, nullptr, out, bu, 4096, 1024, 1024);
}

// Round 4
// 186.802 us; speedup vs baseline: 1.5649x; 1.3983x over previous
//
#include <hip/hip_runtime.h>
#include <hip/hip_bf16.h>

// SelfAttention: x(2,2048,1024) fp32; Wq/Wk/Wv/Wu (1024,1024); bu(1024)
// y = softmax((xWq^T)(xWk^T)^T / 32) (xWv^T) @ Wu^T + bu   (16 heads of 64)
// Attention: swapped-QK^T 32x32 MFMA form — lane owns one q row; softmax fully
// in-register (scalar per lane); PV as O^T = V^T * P^T. Zero LDS, zero barriers.

typedef __bf16 bf16x8 __attribute__((ext_vector_type(8)));
typedef float f32x4 __attribute__((ext_vector_type(4)));
typedef float f32x16 __attribute__((ext_vector_type(16)));
typedef unsigned int u32x4 __attribute__((ext_vector_type(4)));

static __device__ __forceinline__ unsigned short f2bf(float f) {
  union { float f; unsigned u; } a; a.f = f;
  unsigned r = a.u + 0x7fff + ((a.u >> 16) & 1);   // RNE
  return (unsigned short)(r >> 16);
}

static __device__ __forceinline__ unsigned cvt_pk_bf16(float lo, float hi) {
  unsigned r;
  asm("v_cvt_pk_bf16_f32 %0, %1, %2" : "=v"(r) : "v"(lo), "v"(hi));
  return r;
}

// (x', y') = exchange x.hi-lanes with y.lo-lanes:
// x' = lanes<32: x(own) | lanes>=32: y(partner l-32)
// y' = lanes<32: x(partner l+32) | lanes>=32: y(own)
static __device__ __forceinline__ void swap32(unsigned a, unsigned b,
                                              unsigned& x, unsigned& y, int hi) {
#if __has_builtin(__builtin_amdgcn_permlane32_swap)
  typedef unsigned u32x2 __attribute__((ext_vector_type(2)));
  u32x2 r = __builtin_amdgcn_permlane32_swap(a, b, false, false);
  x = r.x; y = r.y;
#else
  unsigned pa = (unsigned)__shfl_xor((int)a, 32, 64);
  unsigned pb = (unsigned)__shfl_xor((int)b, 32, 64);
  x = hi ? pb : a;
  y = hi ? b : pa;
#endif
}

static __device__ __forceinline__ void gload_lds16(const unsigned short* g, unsigned short* l) {
  __builtin_amdgcn_global_load_lds((const __attribute__((address_space(1))) void*)g,
                                   (__attribute__((address_space(3))) void*)l, 16, 0, 0);
}

// Fused bf16 casts: x (4M elems) + 4 weights (1M each). 1024 elems/block.
__global__ __launch_bounds__(256)
void cast_all(const float* __restrict__ x, const float* __restrict__ wq,
              const float* __restrict__ wk, const float* __restrict__ wv,
              const float* __restrict__ wu,
              unsigned short* __restrict__ xb, unsigned short* __restrict__ wqb,
              unsigned short* __restrict__ wkb, unsigned short* __restrict__ wvb,
              unsigned short* __restrict__ wub)
{
  int bid = blockIdx.x;
  const float* src; unsigned short* dst; int blk;
  if (bid < 4096)      { src = x;  dst = xb;  blk = bid; }
  else if (bid < 5120) { src = wq; dst = wqb; blk = bid - 4096; }
  else if (bid < 6144) { src = wk; dst = wkb; blk = bid - 5120; }
  else if (bid < 7168) { src = wv; dst = wvb; blk = bid - 6144; }
  else                 { src = wu; dst = wub; blk = bid - 7168; }
  int idx = blk * 1024 + threadIdx.x * 4;
  float4 v = *(const float4*)&src[idx];
  ushort4 o;
  o.x = f2bf(v.x); o.y = f2bf(v.y); o.z = f2bf(v.z); o.w = f2bf(v.w);
  *(ushort4*)&dst[idx] = o;
}

// Fused Q/K/V GEMM: C = x * W^T (bf16, fp32 accum), z = blockIdx.z picks W.
// 128x128 tile, 8 waves (2x4 of 64x32), BK=32, global_load_lds staging.
// z=0: Q scaled by 1/32, layout [b,h][t][s]; z=1: K, same layout;
// z=2: V transposed layout [b,h][s][t].
__global__ __launch_bounds__(512, 2)
void gemm_qkv(const unsigned short* __restrict__ A,
              const unsigned short* __restrict__ Bq,
              const unsigned short* __restrict__ Bk,
              const unsigned short* __restrict__ Bv,
              unsigned short* __restrict__ Qo,
              unsigned short* __restrict__ Ko,
              unsigned short* __restrict__ Vo)
{
  const int Ksz = 1024;
  __shared__ __align__(16) unsigned short As[128 * 32];
  __shared__ __align__(16) unsigned short Bs[128 * 32];
  const int z = blockIdx.z;
  const unsigned short* B = (z == 0) ? Bq : (z == 1) ? Bk : Bv;
  const int tid  = threadIdx.x;
  const int lane = tid & 63;
  const int wid  = tid >> 6;
  const int wr   = wid >> 2, wc = wid & 3;
  const int g    = lane >> 4, r = lane & 15;
  const int bm   = blockIdx.x * 128, bn = blockIdx.y * 128;

  f32x4 acc[4][2] = {};

  const int grow = lane >> 2;
  const int gcol = (lane & 3) * 8;
  const unsigned short* Ag = &A[(size_t)(bm + wid*16 + grow) * Ksz + gcol];
  const unsigned short* Bg = &B[(size_t)(bn + wid*16 + grow) * Ksz + gcol];
  unsigned short* AsW = &As[wid * 512];
  unsigned short* BsW = &Bs[wid * 512];

  for (int k0 = 0; k0 < Ksz; k0 += 32) {
    __syncthreads();
    gload_lds16(Ag + k0, AsW);
    gload_lds16(Bg + k0, BsW);
    __syncthreads();
    bf16x8 af[4], bfr[2];
#pragma unroll
    for (int mi = 0; mi < 4; ++mi)
      af[mi] = *(const bf16x8*)&As[(wr*64 + mi*16 + r) * 32 + g*8];
#pragma unroll
    for (int ni = 0; ni < 2; ++ni)
      bfr[ni] = *(const bf16x8*)&Bs[(wc*32 + ni*16 + r) * 32 + g*8];
#pragma unroll
    for (int mi = 0; mi < 4; ++mi)
#pragma unroll
      for (int ni = 0; ni < 2; ++ni)
        acc[mi][ni] = __builtin_amdgcn_mfma_f32_16x16x32_bf16(af[mi], bfr[ni], acc[mi][ni], 0, 0, 0);
  }

  const float scale = (z == 0) ? 0.03125f : 1.0f;
#pragma unroll
  for (int mi = 0; mi < 4; ++mi)
#pragma unroll
    for (int ni = 0; ni < 2; ++ni) {
      if (z == 2) {
        int m0 = bm + wr*64 + mi*16 + g*4;
        int n  = bn + wc*32 + ni*16 + r;
        int b = m0 >> 11, t0 = m0 & 2047;
        int h = n >> 6,  s = n & 63;
        ushort4 o;
        o.x = f2bf(acc[mi][ni][0]); o.y = f2bf(acc[mi][ni][1]);
        o.z = f2bf(acc[mi][ni][2]); o.w = f2bf(acc[mi][ni][3]);
        *(ushort4*)&Vo[((size_t)((b*16 + h)*64 + s)) * 2048 + t0] = o;
      } else {
        unsigned short* dst = (z == 0) ? Qo : Ko;
#pragma unroll
        for (int q = 0; q < 4; ++q) {
          int m = bm + wr*64 + mi*16 + g*4 + q;
          int n = bn + wc*32 + ni*16 + r;
          int b = m >> 11, t = m & 2047;
          int h = n >> 6,  s = n & 63;
          dst[((size_t)((b*16 + h)*2048 + t)) * 64 + s] = f2bf(acc[mi][ni][q] * scale);
        }
      }
    }
}

// Final GEMM: out = Ab * Wu^T + bu (fp32 out)
__global__ __launch_bounds__(512, 2)
void gemm_final(const unsigned short* __restrict__ A,
                const unsigned short* __restrict__ B,
                float* __restrict__ Cf,
                const float* __restrict__ bias)
{
  const int Ksz = 1024, N = 1024;
  __shared__ __align__(16) unsigned short As[128 * 32];
  __shared__ __align__(16) unsigned short Bs[128 * 32];
  const int tid  = threadIdx.x;
  const int lane = tid & 63;
  const int wid  = tid >> 6;
  const int wr   = wid >> 2, wc = wid & 3;
  const int g    = lane >> 4, r = lane & 15;
  const int bm   = blockIdx.x * 128, bn = blockIdx.y * 128;

  f32x4 acc[4][2] = {};

  const int grow = lane >> 2;
  const int gcol = (lane & 3) * 8;
  const unsigned short* Ag = &A[(size_t)(bm + wid*16 + grow) * Ksz + gcol];
  const unsigned short* Bg = &B[(size_t)(bn + wid*16 + grow) * Ksz + gcol];
  unsigned short* AsW = &As[wid * 512];
  unsigned short* BsW = &Bs[wid * 512];

  for (int k0 = 0; k0 < Ksz; k0 += 32) {
    __syncthreads();
    gload_lds16(Ag + k0, AsW);
    gload_lds16(Bg + k0, BsW);
    __syncthreads();
    bf16x8 af[4], bfr[2];
#pragma unroll
    for (int mi = 0; mi < 4; ++mi)
      af[mi] = *(const bf16x8*)&As[(wr*64 + mi*16 + r) * 32 + g*8];
#pragma unroll
    for (int ni = 0; ni < 2; ++ni)
      bfr[ni] = *(const bf16x8*)&Bs[(wc*32 + ni*16 + r) * 32 + g*8];
#pragma unroll
    for (int mi = 0; mi < 4; ++mi)
#pragma unroll
      for (int ni = 0; ni < 2; ++ni)
        acc[mi][ni] = __builtin_amdgcn_mfma_f32_16x16x32_bf16(af[mi], bfr[ni], acc[mi][ni], 0, 0, 0);
  }

#pragma unroll
  for (int mi = 0; mi < 4; ++mi)
#pragma unroll
    for (int ni = 0; ni < 2; ++ni)
#pragma unroll
      for (int q = 0; q < 4; ++q) {
        int m = bm + wr*64 + mi*16 + g*4 + q;
        int n = bn + wc*32 + ni*16 + r;
        Cf[(size_t)m * N + n] = acc[mi][ni][q] + bias[n];
      }
}

// Attention, swapped-operand 32x32 form. 512 blocks x 4 waves; wave = 32 q rows.
// Q pre-scaled by 1/32. K,Q,V^T fragments direct from global (L2).
__global__ __launch_bounds__(256)
void attn_kernel(const unsigned short* __restrict__ Qg,
                 const unsigned short* __restrict__ Kg,
                 const unsigned short* __restrict__ Vtg,
                 unsigned short* __restrict__ Og)
{
  const int T = 2048;
  const int lane = threadIdx.x & 63, wid = threadIdx.x >> 6;
  const int q32 = lane & 31;        // own q (and sdim index for V/O)
  const int kh  = lane >> 5;        // lane half

  // XCD-aware swizzle: 4 heads per XCD (K/V working set = 4 MB = one L2)
  int bid  = blockIdx.x;            // 0..511
  int xcd  = bid & 7, slot = bid >> 3;
  int bh   = xcd * 4 + (slot & 3);
  int qblk = slot >> 2;             // 0..15
  int qbase = qblk * 128 + wid * 32;

  const size_t base = (size_t)bh * T * 64;
  const unsigned short* Qh = Qg + base;    // [t][64]
  const unsigned short* Kh = Kg + base;    // [t][64]
  const unsigned short* Vh = Vtg + base;   // [s][T]

  // Q B-fragments: col=lane&31=q, k=(lane>>5)*8+j, 4 k-steps of 16
  bf16x8 qf[4];
#pragma unroll
  for (int s = 0; s < 4; ++s)
    qf[s] = *(const bf16x8*)&Qh[(size_t)(qbase + q32)*64 + s*16 + kh*8];

  f32x16 oacc[2] = {};
  float m = -1e30f, l = 0.f;

#pragma unroll 1
  for (int kv0 = 0; kv0 < T; kv0 += 128) {
    // S^T = K * Q^T: 4 S-tiles of 32 kv; lane gets col=q, rows=kv pattern
    f32x16 sacc[4];
#pragma unroll
    for (int st = 0; st < 4; ++st) {
      f32x16 a = {};
#pragma unroll
      for (int s = 0; s < 4; ++s) {
        bf16x8 kf = *(const bf16x8*)&Kh[(size_t)(kv0 + st*32 + q32)*64 + s*16 + kh*8];
        a = __builtin_amdgcn_mfma_f32_32x32x16_bf16(kf, qf[s], a, 0, 0, 0);
      }
      sacc[st] = a;
    }

    // issue all V loads now; latency hides under softmax VALU/TRANS
    bf16x8 vf[4][2][2];   // [st][chunk][mt]
#pragma unroll
    for (int st = 0; st < 4; ++st)
#pragma unroll
      for (int c = 0; c < 2; ++c)
#pragma unroll
        for (int mt = 0; mt < 2; ++mt)
          vf[st][c][mt] = *(const bf16x8*)&Vh[(size_t)(mt*32 + q32)*T + kv0 + st*32 + c*16 + kh*8];

    // in-register online softmax: lane owns one q row (64 of 128 kv here)
    float pm = -1e30f;
#pragma unroll
    for (int st = 0; st < 4; ++st)
#pragma unroll
      for (int r = 0; r < 16; ++r) pm = fmaxf(pm, sacc[st][r]);
    pm = fmaxf(pm, __shfl_xor(pm, 32, 64));     // combine kv halves
    float mnew = fmaxf(m, pm);
    float fq = __expf(m - mnew);
    m = mnew;
    float rs = 0.f;
#pragma unroll
    for (int st = 0; st < 4; ++st)
#pragma unroll
      for (int r = 0; r < 16; ++r) {
        float p = __expf(sacc[st][r] - mnew);
        sacc[st][r] = p;
        rs += p;
      }
    rs += __shfl_xor(rs, 32, 64);
    l = l * fq + rs;
#pragma unroll
    for (int mt = 0; mt < 2; ++mt)
#pragma unroll
      for (int r = 0; r < 16; ++r) oacc[mt][r] *= fq;

    // pack P -> bf16 B-fragments (cvt_pk + half-swap), then O^T += V^T P^T
#pragma unroll
    for (int st = 0; st < 4; ++st) {
      unsigned U[8];
#pragma unroll
      for (int i = 0; i < 8; ++i)
        U[i] = cvt_pk_bf16(sacc[st][2*i], sacc[st][2*i + 1]);
      unsigned w[8];
      swap32(U[0], U[2], w[0], w[2], kh);
      swap32(U[1], U[3], w[1], w[3], kh);
      swap32(U[4], U[6], w[4], w[6], kh);
      swap32(U[5], U[7], w[5], w[7], kh);
#pragma unroll
      for (int c = 0; c < 2; ++c) {
        u32x4 pw = { w[c*4 + 0], w[c*4 + 1], w[c*4 + 2], w[c*4 + 3] };
        bf16x8 pf = __builtin_bit_cast(bf16x8, pw);
#pragma unroll
        for (int mt = 0; mt < 2; ++mt)
          oacc[mt] = __builtin_amdgcn_mfma_f32_32x32x16_bf16(vf[st][c][mt], pf, oacc[mt], 0, 0, 0);
      }
    }
  }

  // epilogue: O^T/l -> Og[b][t][h*64 + s]; lane owns t = qbase+q32
  const int h = bh & 15, b = bh >> 4;
  const float inv = 1.0f / l;
  const int t = qbase + q32;
#pragma unroll
  for (int mt = 0; mt < 2; ++mt)
#pragma unroll
    for (int rq = 0; rq < 4; ++rq) {
      ushort4 o;
      o.x = f2bf(oacc[mt][rq*4 + 0] * inv);
      o.y = f2bf(oacc[mt][rq*4 + 1] * inv);
      o.z = f2bf(oacc[mt][rq*4 + 2] * inv);
      o.w = f2bf(oacc[mt][rq*4 + 3] * inv);
      int sd = mt*32 + rq*8 + kh*4;
      *(ushort4*)&Og[((size_t)(b*2048 + t))*1024 + h*64 + sd] = o;
    }
}

extern "C" void kernel_launch(void* const* d_in, const int* in_sizes, int n_in,
                              void* d_out, int out_size, void* d_ws, size_t ws_size,
                              hipStream_t stream) {
  const float* x  = (const float*)d_in[0];
  const float* Wq = (const float*)d_in[1];
  const float* Wk = (const float*)d_in[2];
  const float* Wv = (const float*)d_in[3];
  const float* Wu = (const float*)d_in[4];
  const float* bu = (const float*)d_in[5];
  float* out = (float*)d_out;

  char* ws = (char*)d_ws;
  unsigned short* xb  = (unsigned short*)(ws);                 // 8 MB (reused as attn out)
  unsigned short* Wqb = (unsigned short*)(ws + (size_t)( 8<<20));
  unsigned short* Wkb = (unsigned short*)(ws + (size_t)(10<<20));
  unsigned short* Wvb = (unsigned short*)(ws + (size_t)(12<<20));
  unsigned short* Wub = (unsigned short*)(ws + (size_t)(14<<20));
  unsigned short* Qg  = (unsigned short*)(ws + (size_t)(16<<20));
  unsigned short* Kg  = (unsigned short*)(ws + (size_t)(24<<20));
  unsigned short* Vtg = (unsigned short*)(ws + (size_t)(32<<20));
  unsigned short* Ab  = xb;  // attn output overlays xb (dead after QKV GEMMs)

  cast_all<<<dim3(8192), 256, 0, stream>>>(x, Wq, Wk, Wv, Wu, xb, Wqb, Wkb, Wvb, Wub);

  gemm_qkv<<<dim3(32, 8, 3), 512, 0, stream>>>(xb, Wqb, Wkb, Wvb, Qg, Kg, Vtg);

  attn_kernel<<<dim3(512), 256, 0, stream>>>(Qg, Kg, Vtg, Ab);

  gemm_final<<<dim3(32, 8), 512, 0, stream>>>(Ab, Wub, out, bu);
}